// Round 8
// baseline (589.941 us; speedup 1.0000x reference)
//
#include <hip/hip_runtime.h>
#include <hip/hip_bf16.h>
#include <math.h>

typedef __hip_bfloat16 bf16;
typedef unsigned int uint;
typedef unsigned short ushort;
typedef __attribute__((ext_vector_type(8))) short short8;   // 8 bf16 = 4 VGPRs
typedef __attribute__((ext_vector_type(4))) float f32x4;    // MFMA acc

#define HID 128
#define NN 50000
#define NE 800000
#define NG 1024
#define NA 100
#define CAP 64          // fixed CSR bucket capacity (max degree ~45 on this fixed graph)

// ---- two-phase bucketed scatter ----
#define NB   98         // dst buckets (dst >> 9), 512 nodes each
#define RCAP 10240      // records per bucket (mean 8163, sigma ~90 -> very safe)

__device__ __forceinline__ uint bf16_rne_hi(float f) {      // bf16 bits in high 16
    uint u = __float_as_uint(f);
    return (u + 0x7fffu + ((u >> 16) & 1u)) & 0xffff0000u;
}
__device__ __forceinline__ uint pack_bf16x2(float lo, float hi) {
    return (bf16_rne_hi(lo) >> 16) | bf16_rne_hi(hi);
}
__device__ __forceinline__ ushort bf16_rne(float f) {
    uint u = __float_as_uint(f);
    return (ushort)((u + 0x7fffu + ((u >> 16) & 1u)) >> 16);
}
__device__ __forceinline__ float lof(uint u) { return __uint_as_float(u << 16); }
__device__ __forceinline__ float hif(uint u) { return __uint_as_float(u & 0xffff0000u); }
__device__ __forceinline__ float load_f(const void* p, int i, int f32) {
    return f32 ? ((const float*)p)[i]
               : __uint_as_float((uint)((const ushort*)p)[i] << 16);
}
// per-wave dtype detect on raw emb: fp32 read as bf16 -> even elements are
// float low-halves (garbage exponents). 128 probes across 64 lanes.
__device__ __forceinline__ int detect_f32(const void* emb) {
    const ushort* p = (const ushort*)emb;
    int lane = threadIdx.x & 63;
    float v = __uint_as_float((uint)p[lane * 4] << 16);
    int bad0 = (!(v == v) || fabsf(v) > 1e4f || (v != 0.0f && fabsf(v) < 1e-10f));
    float w = __uint_as_float((uint)p[lane * 4 + 2] << 16);
    int bad1 = (!(w == w) || fabsf(w) > 1e4f || (w != 0.0f && fabsf(w) < 1e-10f));
    int cnt = __popcll(__ballot(bad0)) + __popcll(__ballot(bad1));
    return cnt > 16;
}

// ---------- prep: edge phase-A binning + embed(+gpn) + packW + cvt + grf zero ----------
#define A_BLKS     196                        // ceil(800000/4096)
#define EMB_BLKS   ((NN * 64) / 256)          // 12500
#define PACKW_BLKS (5 * 16384 / 256)          // 320
#define CVT_CNT    (300 + 384 + 256 + 128 + 1)// 1069
#define CVT_BLKS   5
#define PR_B1      A_BLKS
#define PR_B2      (PR_B1 + EMB_BLKS)
#define PR_B3      (PR_B2 + PACKW_BLKS)
#define PR_B4      (PR_B3 + CVT_BLKS)
#define PR_B5      (PR_B4 + 4)                // grf zero (1024 floats)
#define PREP_GRID  (PR_B5 + 1)

__global__ void prep_k(const int* __restrict__ xo, const void* __restrict__ emb,
                       const void* __restrict__ gamw, const void* __restrict__ wAW,
                       const void* __restrict__ wAb, const void* __restrict__ linW,
                       const void* __restrict__ linb, const void* __restrict__ wpW,
                       const void* __restrict__ wpb,
                       const int* __restrict__ esrc, const int* __restrict__ edst,
                       const void* __restrict__ ea,
                       uint* __restrict__ xb, ushort* __restrict__ Wp,
                       float* __restrict__ f_sgam, float* __restrict__ f_wAb,
                       float* __restrict__ f_linb, float* __restrict__ f_wp,
                       float* __restrict__ f_wpb,
                       uint2* __restrict__ rec, int* __restrict__ bcur,
                       float* __restrict__ gpn,
                       float* __restrict__ grf, int* __restrict__ flag) {
    int f32 = detect_f32(emb);
    int b = blockIdx.x, t = threadIdx.x;
    if (b < PR_B1) {
        // ---- phase A: bin 4096 edges into NB dst-buckets ----
        __shared__ int hist[NB];
        __shared__ int obase[NB];
        if (t < NB) hist[t] = 0;
        __syncthreads();
        int  dv[16];
        uint rv[16];
#pragma unroll
        for (int k = 0; k < 4; ++k) {
            int e = b * 4096 + k * 1024 + t * 4;
            if (e + 3 < NE) {
                int4 s4 = *(const int4*)(esrc + e);
                int4 d4 = *(const int4*)(edst + e);
                float a0, a1, a2, a3;
                if (f32) {
                    float4 f = *(const float4*)((const float*)ea + e);
                    a0 = f.x; a1 = f.y; a2 = f.z; a3 = f.w;
                } else {
                    ushort4 u = *(const ushort4*)((const ushort*)ea + e);
                    a0 = __uint_as_float((uint)u.x << 16);
                    a1 = __uint_as_float((uint)u.y << 16);
                    a2 = __uint_as_float((uint)u.z << 16);
                    a3 = __uint_as_float((uint)u.w << 16);
                }
                atomicAdd(&hist[d4.x >> 9], 1);
                atomicAdd(&hist[d4.y >> 9], 1);
                atomicAdd(&hist[d4.z >> 9], 1);
                atomicAdd(&hist[d4.w >> 9], 1);
                dv[k * 4 + 0] = d4.x; rv[k * 4 + 0] = (uint)(s4.x & 0xffff) | ((uint)bf16_rne(a0 * a0) << 16);
                dv[k * 4 + 1] = d4.y; rv[k * 4 + 1] = (uint)(s4.y & 0xffff) | ((uint)bf16_rne(a1 * a1) << 16);
                dv[k * 4 + 2] = d4.z; rv[k * 4 + 2] = (uint)(s4.z & 0xffff) | ((uint)bf16_rne(a2 * a2) << 16);
                dv[k * 4 + 3] = d4.w; rv[k * 4 + 3] = (uint)(s4.w & 0xffff) | ((uint)bf16_rne(a3 * a3) << 16);
            } else {
                dv[k * 4 + 0] = dv[k * 4 + 1] = dv[k * 4 + 2] = dv[k * 4 + 3] = -1;
                rv[k * 4 + 0] = rv[k * 4 + 1] = rv[k * 4 + 2] = rv[k * 4 + 3] = 0;
            }
        }
        __syncthreads();
        if (t < NB) {
            int c = hist[t];
            obase[t] = c ? atomicAdd(&bcur[t], c) : 0;   // ONE global atomic per (block,bucket)
            hist[t] = 0;                                 // reuse as running offset
        }
        __syncthreads();
#pragma unroll
        for (int k = 0; k < 16; ++k) {
            int d = dv[k];
            if (d >= 0) {
                int bb = d >> 9;
                int r = atomicAdd(&hist[bb], 1);         // LDS
                int idx = obase[bb] + r;
                if (idx < RCAP) rec[bb * RCAP + idx] = make_uint2(rv[k], (uint)d);
            }
        }
    } else if (b < PR_B2) {
        int gidx = (b - PR_B1) * 256 + t;
        int node = gidx >> 6, c2 = gidx & 63;
        int xon = xo[node];
        int base = xon * HID + c2 * 2;
        xb[gidx] = pack_bf16x2(load_f(emb, base, f32), load_f(emb, base + 1, f32));
        if (c2 < 3) {   // per-node sigmoid(gamma) per layer, hoisted out of gather
            float v = load_f(gamw, c2 * 100 + xon, f32);
            gpn[c2 * NN + node] = 1.0f / (1.0f + __expf(-v));
        }
    } else if (b < PR_B3) {
        // packW: Wp[mat][(ks*8+j16)*64 + q*16 + n][i] = W[mat][ks*32+q*8+i][j16*16+n]
        int t2 = (b - PR_B2) * 256 + t;
        int i   = t2 & 7;
        int n   = (t2 >> 3) & 15;
        int q   = (t2 >> 7) & 3;
        int j16 = (t2 >> 9) & 7;
        int ks  = (t2 >> 12) & 3;
        int mat = t2 >> 14;
        int k = ks * 32 + q * 8 + i;
        int j = j16 * 16 + n;
        const void* W = (mat < 3) ? wAW : linW;
        int off = ((mat < 3) ? mat : (mat - 3)) * 16384 + k * HID + j;
        Wp[t2] = bf16_rne(load_f(W, off, f32));
    } else if (b < PR_B4) {
        int idx = (b - PR_B3) * 256 + t;
        if (idx < 300) {
            float v = load_f(gamw, idx, f32);
            f_sgam[idx] = 1.0f / (1.0f + __expf(-v));
        } else if (idx < 684) {
            f_wAb[idx - 300] = load_f(wAb, idx - 300, f32);
        } else if (idx < 940) {
            f_linb[idx - 684] = load_f(linb, idx - 684, f32);
        } else if (idx < 1068) {
            f_wp[idx - 940] = load_f(wpW, idx - 940, f32);
        } else if (idx < CVT_CNT) {
            f_wpb[0] = load_f(wpb, 0, f32);
        }
    } else if (b < PR_B5) {
        grf[(b - PR_B4) * 256 + t] = 0.0f;
    } else {
        if (t == 0) *flag = f32;
    }
}

// ---------- shared gemm core: wave computes 32 rows x 128 cols ----------
__device__ __forceinline__ void gemm_core(const uint* __restrict__ xb,
                                          const ushort* __restrict__ Wp,
                                          const float* __restrict__ bias,
                                          int m0, int lane,
                                          f32x4 acc0[8], f32x4 acc1[8]) {
    int ln15 = lane & 15;
    int q    = lane >> 4;
    int mA = min(m0 + ln15, NN - 1);
    int mB = min(m0 + 16 + ln15, NN - 1);
    const short8* A8 = (const short8*)xb;
    const short8* B8 = (const short8*)Wp;
#pragma unroll
    for (int j16 = 0; j16 < 8; ++j16) {
        float bv = bias[j16 * 16 + ln15];
        acc0[j16] = (f32x4){bv, bv, bv, bv};
        acc1[j16] = acc0[j16];
    }
#pragma unroll
    for (int ks = 0; ks < 4; ++ks) {
        short8 a0 = A8[mA * 16 + ks * 4 + q];
        short8 a1 = A8[mB * 16 + ks * 4 + q];
#pragma unroll
        for (int j16 = 0; j16 < 8; ++j16) {
            short8 b = B8[(ks * 8 + j16) * 64 + q * 16 + ln15];
            acc0[j16] = __builtin_amdgcn_mfma_f32_16x16x32_bf16(a0, b, acc0[j16], 0, 0, 0);
            acc1[j16] = __builtin_amdgcn_mfma_f32_16x16x32_bf16(a1, b, acc1[j16], 0, 0, 0);
        }
    }
}

__device__ __forceinline__ void gemm_store(f32x4 acc0[8], f32x4 acc1[8],
                                           int m0, int lane, uint* __restrict__ outb) {
    int ln15 = lane & 15;
    int q    = lane >> 4;
    ushort* ob = (ushort*)outb;
#pragma unroll
    for (int reg = 0; reg < 4; ++reg) {
        int n0 = m0 + q * 4 + reg;
        int n1 = n0 + 16;
#pragma unroll
        for (int j16 = 0; j16 < 8; ++j16) {
            if (n0 < NN)
                ob[(size_t)n0 * HID + j16 * 16 + ln15] = bf16_rne(fmaxf(acc0[j16][reg], 0.0f));
            if (n1 < NN)
                ob[(size_t)n1 * HID + j16 * 16 + ln15] = bf16_rne(fmaxf(acc1[j16][reg], 0.0f));
        }
    }
}

// ---------- work2: phase-B CSR build (blocks 0..NB-1) ∥ gemm layer-1 (rest) ----------
#define G1_BLKS ((NN + 255) / 256)     // 196 gemm blocks of 256 rows (8 waves x 32)
__global__ __launch_bounds__(512) void work2_k(const uint* __restrict__ xb,
                                               const ushort* __restrict__ Wp,
                                               const float* __restrict__ bias,
                                               uint* __restrict__ outb,
                                               const uint2* __restrict__ rec,
                                               const int* __restrict__ bcur,
                                               uint* __restrict__ csr,
                                               int* __restrict__ degarr) {
    int b = blockIdx.x, t = threadIdx.x;
    if (b < NB) {
        // one block per bucket: per-node cursors in LDS, csr slice is L2-resident
        __shared__ int ldeg[512];
        ldeg[t] = 0;
        __syncthreads();
        int cnt = min(bcur[b], RCAP);
        int nb0 = b << 9;
        for (int i = t; i < cnt; i += 512) {
            uint2 r = rec[b * RCAP + i];
            int dst = (int)r.y;
            int p = atomicAdd(&ldeg[dst - nb0], 1);      // LDS atomic
            if (p < CAP) csr[dst * CAP + p] = r.x;
        }
        __syncthreads();
        int n = nb0 + t;
        if (n < NN) degarr[n] = min(ldeg[t], CAP);
    } else {
        f32x4 acc0[8], acc1[8];
        int m0 = (b - NB) * 256 + (t >> 6) * 32;
        gemm_core(xb, Wp, bias, m0, t & 63, acc0, acc1);
        gemm_store(acc0, acc1, m0, t & 63, outb);
    }
}

// ---------- gq: XCD-column-sharded gather (pass A) ----------
// agg[n, quarter] = sum_e exp(-g*w2)*h[src, quarter]. One wave per node-quarter;
// 64 lanes = 4 edge-slots x 16 col-lanes (quarter = 32 cols = 64 B). Block->XCD is
// round-robin (b%8), so quarter = slot&3 pins XCD k to quarter k&3 whose hb slice
// (50000x64B = 3.2 MB) is L2-resident -> random row reads become L2 hits. csr/agg
// use non-temporal ops so streams don't evict the hot slice. Perf heuristic only:
// correctness never depends on the XCD mapping. Writes bf16 agg (rounding ~0.4%).
#define GQ_GRID ((NN / 8 / 2) * 8)     // 3125 tile-pairs x 8 slots = 25000
__global__ __launch_bounds__(512) void gq_k(const int* __restrict__ degarr,
                                            const uint* __restrict__ csr,
                                            const float* __restrict__ gpnl,
                                            const uint* __restrict__ hb_in,
                                            uint* __restrict__ aggb) {
    int t = threadIdx.x, w = t >> 6, lane = t & 63;
    int slot4 = lane >> 4, l15 = lane & 15;
    int b = blockIdx.x, pair = b >> 3, slot = b & 7;
    int qt   = slot & 3;                  // quarter (32 cols), pinned to XCD b%8
    int tile = pair * 2 + (slot >> 2);    // node tile (8 nodes)
    int n = tile * 8 + w;                 // always < NN (50000 = 6250*8 exact)
    int cu = qt * 16 + l15;               // uint index within row (2 cols)
    int deg = degarr[n];
    const uint* cp = csr + (size_t)n * CAP;
    float g = gpnl[n];
    float ax = 0.0f, ay = 0.0f;
    uint cc = __builtin_nontemporal_load(cp + slot4);
    for (int e = 0; e < deg; e += 4) {
        uint cn = __builtin_nontemporal_load(cp + e + 4 + slot4);  // prefetch (over-read in ws, masked)
        bool vld = (e + slot4) < deg;
        float wi = vld ? __expf(-g * hif(cc)) : 0.0f;
        int   ri = vld ? (int)(cc & 0xffffu) : 0;
        uint  v  = hb_in[(size_t)ri * 64 + cu];    // 64B/slot-group, L2-resident slice
        ax = fmaf(wi, lof(v), ax);
        ay = fmaf(wi, hif(v), ay);
        cc = cn;
    }
    // reduce across the 4 edge-slots
    ax += __shfl_xor(ax, 16); ax += __shfl_xor(ax, 32);
    ay += __shfl_xor(ay, 16); ay += __shfl_xor(ay, 32);
    if (slot4 == 0)
        __builtin_nontemporal_store(pack_bf16x2(ax, ay), &aggb[(size_t)n * 64 + cu]);
}

// ---------- ng: norm (pass B) + gemm; LAST=1 fuses lin1 + wp proj + graph sum ----------
template<int LAST>
__global__ __launch_bounds__(512) void ng_k(const uint* __restrict__ aggb,
                                            uint* __restrict__ xb,
                                            const ushort* __restrict__ Wp,
                                            const float* __restrict__ bias,
                                            uint* __restrict__ hb_out,
                                            const ushort* __restrict__ Wp2,
                                            const float* __restrict__ bias2,
                                            const float* __restrict__ wp,
                                            const int* __restrict__ batch,
                                            float* __restrict__ grf) {
    __shared__ uint  lds_a[2048];                 // 8 KB A-frag tile
    __shared__ uint  lds_b[LAST ? 2048 : 1];      // staged h tile (LAST only)
    __shared__ float lds_p[LAST ? 256 : 1];       // per-(row,wave) projection partials
    int t = threadIdx.x;
    int w = t >> 6, lane = t & 63;
    int q = lane >> 4, ln15 = lane & 15;
    int n0 = blockIdx.x * 32;

    // ---- phase 1: y = agg + x, full-row norm (16-lane shfl), normalize ----
    {
        int j  = w * 4 + q;              // row within block tile (0..31)
        int n  = n0 + j;
        int nc = min(n, NN - 1);
        uint4 av = *(const uint4*)(aggb + (size_t)nc * 64 + ln15 * 4);
        uint4 xv = *(const uint4*)(xb   + (size_t)nc * 64 + ln15 * 4);
        float yx0 = lof(av.x) + lof(xv.x), yy0 = hif(av.x) + hif(xv.x);
        float yx1 = lof(av.y) + lof(xv.y), yy1 = hif(av.y) + hif(xv.y);
        float yx2 = lof(av.z) + lof(xv.z), yy2 = hif(av.z) + hif(xv.z);
        float yx3 = lof(av.w) + lof(xv.w), yy3 = hif(av.w) + hif(xv.w);
        float ss = yx0 * yx0 + yy0 * yy0 + yx1 * yx1 + yy1 * yy1
                 + yx2 * yx2 + yy2 * yy2 + yx3 * yx3 + yy3 * yy3;
        ss += __shfl_xor(ss, 1); ss += __shfl_xor(ss, 2);
        ss += __shfl_xor(ss, 4); ss += __shfl_xor(ss, 8);
        float inv = 1.0f / fmaxf(sqrtf(ss), 1e-12f);
        uint4 o;
        o.x = pack_bf16x2(yx0 * inv, yy0 * inv);
        o.y = pack_bf16x2(yx1 * inv, yy1 * inv);
        o.z = pack_bf16x2(yx2 * inv, yy2 * inv);
        o.w = pack_bf16x2(yx3 * inv, yy3 * inv);
        if (!LAST && n < NN) *(uint4*)(xb + (size_t)n * 64 + ln15 * 4) = o;
        // LDS A-frag layout (verified): contiguous for the 4 col-pairs -> ds_write_b128
        int rt = j >> 4, m = j & 15;
        *(uint4*)&lds_a[(((rt * 4 + (ln15 >> 2)) * 64) + (ln15 & 3) * 16 + m) * 4] = o;
    }
    __syncthreads();

    // ---- phase 2: gemm, wave w = j16 strip w ----
    const short8* A8 = (const short8*)lds_a;
    const short8* B8 = (const short8*)Wp;
    f32x4 acc[2];
    {
        float bv = bias[w * 16 + ln15];
        acc[0] = (f32x4){bv, bv, bv, bv};
        acc[1] = acc[0];
    }
#pragma unroll
    for (int ks = 0; ks < 4; ++ks) {
        short8 b = B8[(ks * 8 + w) * 64 + lane];
#pragma unroll
        for (int rt = 0; rt < 2; ++rt) {
            short8 a = A8[(rt * 4 + ks) * 64 + lane];
            acc[rt] = __builtin_amdgcn_mfma_f32_16x16x32_bf16(a, b, acc[rt], 0, 0, 0);
        }
    }
    if (!LAST) {
        ushort* ob = (ushort*)hb_out;
#pragma unroll
        for (int rt = 0; rt < 2; ++rt) {
#pragma unroll
            for (int reg = 0; reg < 4; ++reg) {
                int nn = n0 + rt * 16 + q * 4 + reg;
                if (nn < NN)
                    ob[(size_t)nn * HID + w * 16 + ln15] = bf16_rne(fmaxf(acc[rt][reg], 0.0f));
            }
        }
    } else {
        // ---- stage h tile into lds_b in A-frag layout (bf16, same rounding as before) ----
        ushort* sb = (ushort*)lds_b;
        int c  = w * 16 + ln15;          // column this thread owns
        int c2 = c >> 1, cb = c2 & 3, cq = (c2 >> 2) & 3, cks = c2 >> 4, lohi = c & 1;
#pragma unroll
        for (int rt = 0; rt < 2; ++rt) {
#pragma unroll
            for (int reg = 0; reg < 4; ++reg) {
                int m = q * 4 + reg;     // row & 15
                int uidx = ((rt * 4 + cks) * 64 + cq * 16 + m) * 4 + cb;
                sb[uidx * 2 + lohi] = bf16_rne(fmaxf(acc[rt][reg], 0.0f));
            }
        }
        __syncthreads();
        // ---- phase 3: lin1 gemm from lds_b ----
        const short8* A8b = (const short8*)lds_b;
        const short8* B8b = (const short8*)Wp2;
        f32x4 acc3[2];
        {
            float bv = bias2[w * 16 + ln15];
            acc3[0] = (f32x4){bv, bv, bv, bv};
            acc3[1] = acc3[0];
        }
#pragma unroll
        for (int ks = 0; ks < 4; ++ks) {
            short8 bb = B8b[(ks * 8 + w) * 64 + lane];
#pragma unroll
            for (int rt = 0; rt < 2; ++rt) {
                short8 a = A8b[(rt * 4 + ks) * 64 + lane];
                acc3[rt] = __builtin_amdgcn_mfma_f32_16x16x32_bf16(a, bb, acc3[rt], 0, 0, 0);
            }
        }
        // ---- projection: s(row) = sum_j relu(h2)_j * wp_j, then graph segment-sum ----
        float wv = wp[w * 16 + ln15];
#pragma unroll
        for (int rt = 0; rt < 2; ++rt) {
#pragma unroll
            for (int reg = 0; reg < 4; ++reg) {
                float p = fmaxf(acc3[rt][reg], 0.0f) * wv;
                p += __shfl_xor(p, 1); p += __shfl_xor(p, 2);
                p += __shfl_xor(p, 4); p += __shfl_xor(p, 8);
                if (ln15 == 0) lds_p[(rt * 16 + q * 4 + reg) * 8 + w] = p;
            }
        }
        __syncthreads();
        if (t < 32) {
            float sm = 0.0f;
#pragma unroll
            for (int k = 0; k < 8; ++k) sm += lds_p[t * 8 + k];
            int nn = n0 + t;
            if (nn < NN) atomicAdd(&grf[batch[nn]], sm);
        }
    }
}

// ---------- out conversion: out[g] = grf[g] + wpb ----------
__global__ void out_k(const float* __restrict__ grf, const float* __restrict__ wpb,
                      void* __restrict__ out, const int* __restrict__ flag) {
    int g = blockIdx.x * 256 + threadIdx.x;
    if (g >= NG) return;
    float r = grf[g] + wpb[0];
    if (*flag) ((float*)out)[g] = r;
    else       ((bf16*)out)[g] = __float2bfloat16(r);
}

extern "C" void kernel_launch(void* const* d_in, const int* in_sizes, int n_in,
                              void* d_out, int out_size, void* d_ws, size_t ws_size,
                              hipStream_t stream) {
    const int*  xo    = (const int*)d_in[0];
    const int*  ei    = (const int*)d_in[1];
    const int*  src   = ei;
    const int*  dst   = ei + NE;
    const void* ea    = d_in[2];
    const int*  batch = (const int*)d_in[3];
    const void* emb   = d_in[4];
    const void* gamw  = d_in[5];
    const void* wAW   = d_in[6];
    const void* wAb   = d_in[7];
    const void* linW  = d_in[8];
    const void* linb  = d_in[9];
    const void* wpW   = d_in[10];
    const void* wpb   = d_in[11];

    uint*  xb     = (uint*)d_ws;                           // NN*64 (12.8 MB)
    uint*  hA     = xb + (size_t)NN * 64;                  // NN*64 (12.8 MB)
    uint*  hB     = hA + (size_t)NN * 64;                  // NN*64 (12.8 MB)
    uint2* rec    = (uint2*)hB;                            // alias: NB*RCAP*8B = 8.0 MB,
                                                           // dead before ng1 writes hB
    uint*  csr    = hB + (size_t)NN * 64;                  // NN*CAP (12.8 MB)
    int*   degarr = (int*)(csr + (size_t)NN * CAP);        // NN
    float* grf    = (float*)(degarr + NN);                 // NG
    float* P      = grf + NG;
    float* f_sgam = P;                 // 300 (+pad)
    float* f_wAb  = f_sgam + 304;      // 384
    float* f_linb = f_wAb + 384;       // 256
    float* f_wp   = f_linb + 256;      // 128
    float* f_wpb  = f_wp + 128;        // 1 (+pad)
    int*   flag   = (int*)(f_wpb + 8);
    ushort* Wp    = (ushort*)(flag + 8);   // 5*16384 bf16
    int*   bcur   = (int*)(Wp + 5 * 16384); // NB bucket cursors (+pad)
    float* gpn    = (float*)(bcur + 128);   // 3*NN per-node sigmoid(gamma)
    uint*  aggb   = (uint*)(gpn + 3 * NN);  // NN*64 bf16x2 aggregate (12.8 MB)

    hipMemsetAsync(bcur, 0, NB * sizeof(int), stream);

    prep_k<<<PREP_GRID, 256, 0, stream>>>(xo, emb, gamw, wAW, wAb, linW, linb, wpW, wpb,
                                          src, dst, ea,
                                          xb, Wp, f_sgam, f_wAb, f_linb, f_wp, f_wpb,
                                          rec, bcur, gpn, grf, flag);

    // phase-B CSR build (98 bucket blocks) overlapped with gemm layer-1 (xb -> hA)
    work2_k<<<NB + G1_BLKS, 512, 0, stream>>>(xb, Wp, f_wAb, hA, rec, bcur, csr, degarr);

    const int GG_GRID = (NN + 31) / 32;   // 1563
    // layer 1: col-sharded gather(hA) -> agg; norm + gemm2 -> hB, xb=x1
    gq_k<<<GQ_GRID, 512, 0, stream>>>(degarr, csr, gpn,          hA, aggb);
    ng_k<0><<<GG_GRID, 512, 0, stream>>>(aggb, xb, Wp + 1 * 16384, f_wAb + 128, hB,
                                         nullptr, nullptr, nullptr, nullptr, nullptr);
    // layer 2: gather(hB) -> agg; norm + gemm3 -> hA, xb=x2
    gq_k<<<GQ_GRID, 512, 0, stream>>>(degarr, csr, gpn + NN,     hB, aggb);
    ng_k<0><<<GG_GRID, 512, 0, stream>>>(aggb, xb, Wp + 2 * 16384, f_wAb + 256, hA,
                                         nullptr, nullptr, nullptr, nullptr, nullptr);
    // layer 3: gather(hA) -> agg; norm + lin0 + lin1 + proj -> grf
    gq_k<<<GQ_GRID, 512, 0, stream>>>(degarr, csr, gpn + 2 * NN, hA, aggb);
    ng_k<1><<<GG_GRID, 512, 0, stream>>>(aggb, xb, Wp + 3 * 16384, f_linb, nullptr,
                                         Wp + 4 * 16384, f_linb + HID, f_wp, batch, grf);

    out_k<<<(NG + 255) / 256, 256, 0, stream>>>(grf, f_wpb, d_out, flag);
}

// Round 9
// 263.855 us; speedup vs baseline: 2.2359x; 2.2359x over previous
//
#include <hip/hip_runtime.h>
#include <hip/hip_bf16.h>
#include <math.h>

typedef __hip_bfloat16 bf16;
typedef unsigned int uint;
typedef unsigned short ushort;
typedef __attribute__((ext_vector_type(8))) short short8;   // 8 bf16 = 4 VGPRs
typedef __attribute__((ext_vector_type(4))) float f32x4;    // MFMA acc

#define HID 128
#define NN 50000
#define NE 800000
#define NG 1024
#define NA 100
#define CAP 64          // fixed CSR bucket capacity (max degree ~45 on this fixed graph)

// ---- two-phase bucketed scatter ----
#define NB   98         // dst buckets (dst >> 9), 512 nodes each
#define RCAP 10240      // records per bucket (mean 8163, sigma ~90 -> very safe)

__device__ __forceinline__ uint bf16_rne_hi(float f) {      // bf16 bits in high 16
    uint u = __float_as_uint(f);
    return (u + 0x7fffu + ((u >> 16) & 1u)) & 0xffff0000u;
}
__device__ __forceinline__ uint pack_bf16x2(float lo, float hi) {
    return (bf16_rne_hi(lo) >> 16) | bf16_rne_hi(hi);
}
__device__ __forceinline__ ushort bf16_rne(float f) {
    uint u = __float_as_uint(f);
    return (ushort)((u + 0x7fffu + ((u >> 16) & 1u)) >> 16);
}
__device__ __forceinline__ float lof(uint u) { return __uint_as_float(u << 16); }
__device__ __forceinline__ float hif(uint u) { return __uint_as_float(u & 0xffff0000u); }
__device__ __forceinline__ float load_f(const void* p, int i, int f32) {
    return f32 ? ((const float*)p)[i]
               : __uint_as_float((uint)((const ushort*)p)[i] << 16);
}
// per-wave dtype detect on raw emb: fp32 read as bf16 -> even elements are
// float low-halves (garbage exponents). 128 probes across 64 lanes.
__device__ __forceinline__ int detect_f32(const void* emb) {
    const ushort* p = (const ushort*)emb;
    int lane = threadIdx.x & 63;
    float v = __uint_as_float((uint)p[lane * 4] << 16);
    int bad0 = (!(v == v) || fabsf(v) > 1e4f || (v != 0.0f && fabsf(v) < 1e-10f));
    float w = __uint_as_float((uint)p[lane * 4 + 2] << 16);
    int bad1 = (!(w == w) || fabsf(w) > 1e4f || (w != 0.0f && fabsf(w) < 1e-10f));
    int cnt = __popcll(__ballot(bad0)) + __popcll(__ballot(bad1));
    return cnt > 16;
}

// ---------- prep: edge phase-A binning + embed(+gpn) + packW + cvt + grf zero ----------
#define A_BLKS     196                        // ceil(800000/4096)
#define EMB_BLKS   ((NN * 64) / 256)          // 12500
#define PACKW_BLKS (5 * 16384 / 256)          // 320
#define CVT_CNT    (300 + 384 + 256 + 128 + 1)// 1069
#define CVT_BLKS   5
#define PR_B1      A_BLKS
#define PR_B2      (PR_B1 + EMB_BLKS)
#define PR_B3      (PR_B2 + PACKW_BLKS)
#define PR_B4      (PR_B3 + CVT_BLKS)
#define PR_B5      (PR_B4 + 4)                // grf zero (1024 floats)
#define PREP_GRID  (PR_B5 + 1)

__global__ void prep_k(const int* __restrict__ xo, const void* __restrict__ emb,
                       const void* __restrict__ gamw, const void* __restrict__ wAW,
                       const void* __restrict__ wAb, const void* __restrict__ linW,
                       const void* __restrict__ linb, const void* __restrict__ wpW,
                       const void* __restrict__ wpb,
                       const int* __restrict__ esrc, const int* __restrict__ edst,
                       const void* __restrict__ ea,
                       uint* __restrict__ xb, ushort* __restrict__ Wp,
                       float* __restrict__ f_sgam, float* __restrict__ f_wAb,
                       float* __restrict__ f_linb, float* __restrict__ f_wp,
                       float* __restrict__ f_wpb,
                       uint2* __restrict__ rec, int* __restrict__ bcur,
                       float* __restrict__ gpn,
                       float* __restrict__ grf, int* __restrict__ flag) {
    int f32 = detect_f32(emb);
    int b = blockIdx.x, t = threadIdx.x;
    if (b < PR_B1) {
        // ---- phase A: bin 4096 edges into NB dst-buckets ----
        __shared__ int hist[NB];
        __shared__ int obase[NB];
        if (t < NB) hist[t] = 0;
        __syncthreads();
        int  dv[16];
        uint rv[16];
#pragma unroll
        for (int k = 0; k < 4; ++k) {
            int e = b * 4096 + k * 1024 + t * 4;
            if (e + 3 < NE) {
                int4 s4 = *(const int4*)(esrc + e);
                int4 d4 = *(const int4*)(edst + e);
                float a0, a1, a2, a3;
                if (f32) {
                    float4 f = *(const float4*)((const float*)ea + e);
                    a0 = f.x; a1 = f.y; a2 = f.z; a3 = f.w;
                } else {
                    ushort4 u = *(const ushort4*)((const ushort*)ea + e);
                    a0 = __uint_as_float((uint)u.x << 16);
                    a1 = __uint_as_float((uint)u.y << 16);
                    a2 = __uint_as_float((uint)u.z << 16);
                    a3 = __uint_as_float((uint)u.w << 16);
                }
                atomicAdd(&hist[d4.x >> 9], 1);
                atomicAdd(&hist[d4.y >> 9], 1);
                atomicAdd(&hist[d4.z >> 9], 1);
                atomicAdd(&hist[d4.w >> 9], 1);
                dv[k * 4 + 0] = d4.x; rv[k * 4 + 0] = (uint)(s4.x & 0xffff) | ((uint)bf16_rne(a0 * a0) << 16);
                dv[k * 4 + 1] = d4.y; rv[k * 4 + 1] = (uint)(s4.y & 0xffff) | ((uint)bf16_rne(a1 * a1) << 16);
                dv[k * 4 + 2] = d4.z; rv[k * 4 + 2] = (uint)(s4.z & 0xffff) | ((uint)bf16_rne(a2 * a2) << 16);
                dv[k * 4 + 3] = d4.w; rv[k * 4 + 3] = (uint)(s4.w & 0xffff) | ((uint)bf16_rne(a3 * a3) << 16);
            } else {
                dv[k * 4 + 0] = dv[k * 4 + 1] = dv[k * 4 + 2] = dv[k * 4 + 3] = -1;
                rv[k * 4 + 0] = rv[k * 4 + 1] = rv[k * 4 + 2] = rv[k * 4 + 3] = 0;
            }
        }
        __syncthreads();
        if (t < NB) {
            int c = hist[t];
            obase[t] = c ? atomicAdd(&bcur[t], c) : 0;   // ONE global atomic per (block,bucket)
            hist[t] = 0;                                 // reuse as running offset
        }
        __syncthreads();
#pragma unroll
        for (int k = 0; k < 16; ++k) {
            int d = dv[k];
            if (d >= 0) {
                int bb = d >> 9;
                int r = atomicAdd(&hist[bb], 1);         // LDS
                int idx = obase[bb] + r;
                if (idx < RCAP) rec[bb * RCAP + idx] = make_uint2(rv[k], (uint)d);
            }
        }
    } else if (b < PR_B2) {
        int gidx = (b - PR_B1) * 256 + t;
        int node = gidx >> 6, c2 = gidx & 63;
        int xon = xo[node];
        int base = xon * HID + c2 * 2;
        xb[gidx] = pack_bf16x2(load_f(emb, base, f32), load_f(emb, base + 1, f32));
        if (c2 < 3) {   // per-node sigmoid(gamma) per layer, hoisted out of gather
            float v = load_f(gamw, c2 * 100 + xon, f32);
            gpn[c2 * NN + node] = 1.0f / (1.0f + __expf(-v));
        }
    } else if (b < PR_B3) {
        // packW: Wp[mat][(ks*8+j16)*64 + q*16 + n][i] = W[mat][ks*32+q*8+i][j16*16+n]
        int t2 = (b - PR_B2) * 256 + t;
        int i   = t2 & 7;
        int n   = (t2 >> 3) & 15;
        int q   = (t2 >> 7) & 3;
        int j16 = (t2 >> 9) & 7;
        int ks  = (t2 >> 12) & 3;
        int mat = t2 >> 14;
        int k = ks * 32 + q * 8 + i;
        int j = j16 * 16 + n;
        const void* W = (mat < 3) ? wAW : linW;
        int off = ((mat < 3) ? mat : (mat - 3)) * 16384 + k * HID + j;
        Wp[t2] = bf16_rne(load_f(W, off, f32));
    } else if (b < PR_B4) {
        int idx = (b - PR_B3) * 256 + t;
        if (idx < 300) {
            float v = load_f(gamw, idx, f32);
            f_sgam[idx] = 1.0f / (1.0f + __expf(-v));
        } else if (idx < 684) {
            f_wAb[idx - 300] = load_f(wAb, idx - 300, f32);
        } else if (idx < 940) {
            f_linb[idx - 684] = load_f(linb, idx - 684, f32);
        } else if (idx < 1068) {
            f_wp[idx - 940] = load_f(wpW, idx - 940, f32);
        } else if (idx < CVT_CNT) {
            f_wpb[0] = load_f(wpb, 0, f32);
        }
    } else if (b < PR_B5) {
        grf[(b - PR_B4) * 256 + t] = 0.0f;
    } else {
        if (t == 0) *flag = f32;
    }
}

// ---------- shared gemm core: wave computes 32 rows x 128 cols ----------
__device__ __forceinline__ void gemm_core(const uint* __restrict__ xb,
                                          const ushort* __restrict__ Wp,
                                          const float* __restrict__ bias,
                                          int m0, int lane,
                                          f32x4 acc0[8], f32x4 acc1[8]) {
    int ln15 = lane & 15;
    int q    = lane >> 4;
    int mA = min(m0 + ln15, NN - 1);
    int mB = min(m0 + 16 + ln15, NN - 1);
    const short8* A8 = (const short8*)xb;
    const short8* B8 = (const short8*)Wp;
#pragma unroll
    for (int j16 = 0; j16 < 8; ++j16) {
        float bv = bias[j16 * 16 + ln15];
        acc0[j16] = (f32x4){bv, bv, bv, bv};
        acc1[j16] = acc0[j16];
    }
#pragma unroll
    for (int ks = 0; ks < 4; ++ks) {
        short8 a0 = A8[mA * 16 + ks * 4 + q];
        short8 a1 = A8[mB * 16 + ks * 4 + q];
#pragma unroll
        for (int j16 = 0; j16 < 8; ++j16) {
            short8 b = B8[(ks * 8 + j16) * 64 + q * 16 + ln15];
            acc0[j16] = __builtin_amdgcn_mfma_f32_16x16x32_bf16(a0, b, acc0[j16], 0, 0, 0);
            acc1[j16] = __builtin_amdgcn_mfma_f32_16x16x32_bf16(a1, b, acc1[j16], 0, 0, 0);
        }
    }
}

__device__ __forceinline__ void gemm_store(f32x4 acc0[8], f32x4 acc1[8],
                                           int m0, int lane, uint* __restrict__ outb) {
    int ln15 = lane & 15;
    int q    = lane >> 4;
    ushort* ob = (ushort*)outb;
#pragma unroll
    for (int reg = 0; reg < 4; ++reg) {
        int n0 = m0 + q * 4 + reg;
        int n1 = n0 + 16;
#pragma unroll
        for (int j16 = 0; j16 < 8; ++j16) {
            if (n0 < NN)
                ob[(size_t)n0 * HID + j16 * 16 + ln15] = bf16_rne(fmaxf(acc0[j16][reg], 0.0f));
            if (n1 < NN)
                ob[(size_t)n1 * HID + j16 * 16 + ln15] = bf16_rne(fmaxf(acc1[j16][reg], 0.0f));
        }
    }
}

// ---------- work2: phase-B CSR build (blocks 0..NB-1) ∥ gemm layer-1 (rest) ----------
#define G1_BLKS ((NN + 255) / 256)     // 196 gemm blocks of 256 rows (8 waves x 32)
__global__ __launch_bounds__(512) void work2_k(const uint* __restrict__ xb,
                                               const ushort* __restrict__ Wp,
                                               const float* __restrict__ bias,
                                               uint* __restrict__ outb,
                                               const uint2* __restrict__ rec,
                                               const int* __restrict__ bcur,
                                               uint* __restrict__ csr,
                                               int* __restrict__ degarr) {
    int b = blockIdx.x, t = threadIdx.x;
    if (b < NB) {
        // one block per bucket: per-node cursors in LDS, csr slice is L2-resident
        __shared__ int ldeg[512];
        ldeg[t] = 0;
        __syncthreads();
        int cnt = min(bcur[b], RCAP);
        int nb0 = b << 9;
        for (int i = t; i < cnt; i += 512) {
            uint2 r = rec[b * RCAP + i];
            int dst = (int)r.y;
            int p = atomicAdd(&ldeg[dst - nb0], 1);      // LDS atomic
            if (p < CAP) csr[dst * CAP + p] = r.x;
        }
        __syncthreads();
        int n = nb0 + t;
        if (n < NN) degarr[n] = min(ldeg[t], CAP);
    } else {
        f32x4 acc0[8], acc1[8];
        int m0 = (b - NB) * 256 + (t >> 6) * 32;
        gemm_core(xb, Wp, bias, m0, t & 63, acc0, acc1);
        gemm_store(acc0, acc1, m0, t & 63, outb);
    }
}

// ---------- GG: fused gather+norm (layer l) -> gemm (layer l+1), 32 nodes/block ----------
// Phase 1: lane = (node q, col-block ln15); csr words DOUBLE-BUFFERED (the word for
// step e+4 is prefetched while step e's four row-gathers are in flight -> exposed
// latency per iteration drops from L_csr + L_gather to ~L_gather); xb residual load
// hoisted above the loop. LAST=1 fuses lin1 + wp projection + per-graph segment sum.
template<int LAST>
__global__ __launch_bounds__(512) void gg_k(const int* __restrict__ degarr,
                                            const uint* __restrict__ csr,
                                            const float* __restrict__ gpn,
                                            const uint* __restrict__ hb_in,
                                            uint* __restrict__ xb,
                                            const ushort* __restrict__ Wp,
                                            const float* __restrict__ bias,
                                            uint* __restrict__ hb_out,
                                            const ushort* __restrict__ Wp2,
                                            const float* __restrict__ bias2,
                                            const float* __restrict__ wp,
                                            const int* __restrict__ batch,
                                            float* __restrict__ grf) {
    __shared__ uint  lds_a[2048];                 // 8 KB A-frag tile
    __shared__ uint  lds_b[LAST ? 2048 : 1];      // staged h tile (LAST only)
    __shared__ float lds_p[LAST ? 256 : 1];       // per-(row,wave) projection partials
    int t = threadIdx.x;
    int w = t >> 6, lane = t & 63;
    int q = lane >> 4, ln15 = lane & 15;
    int n0 = blockIdx.x * 32;

    // ---- phase 1: gather + residual + normalize; group q owns node n0+w*4+q ----
    int j  = w * 4 + q;              // row within block tile (0..31)
    int n  = n0 + j;
    int nc = min(n, NN - 1);
    int deg = (n < NN) ? degarr[n] : 0;
    const uint* cp = csr + (size_t)nc * CAP;
    float g = gpn[nc];
    uint4 xv = *(const uint4*)(xb + (size_t)nc * 64 + ln15 * 4);   // hoisted (independent)
    float ax0 = 0.f, ax1 = 0.f, ax2 = 0.f, ax3 = 0.f;
    float ay0 = 0.f, ay1 = 0.f, ay2 = 0.f, ay3 = 0.f;
    uint4 c4 = *(const uint4*)(cp);                                // prologue csr word
    for (int e = 0; e < deg; e += 4) {
        uint4 c4n = *(const uint4*)(cp + e + 4);   // prefetch next word (in workspace, masked)
        uint cc[4] = {c4.x, c4.y, c4.z, c4.w};
#pragma unroll
        for (int i = 0; i < 4; ++i) {
            bool vld = (e + i) < deg;
            float wi = vld ? __expf(-g * hif(cc[i])) : 0.0f;
            int   ri = vld ? (int)(cc[i] & 0xffffu) : 0;
            uint4 v  = *(const uint4*)(hb_in + (size_t)ri * 64 + ln15 * 4);
            ax0 = fmaf(wi, lof(v.x), ax0); ay0 = fmaf(wi, hif(v.x), ay0);
            ax1 = fmaf(wi, lof(v.y), ax1); ay1 = fmaf(wi, hif(v.y), ay1);
            ax2 = fmaf(wi, lof(v.z), ax2); ay2 = fmaf(wi, hif(v.z), ay2);
            ax3 = fmaf(wi, lof(v.w), ax3); ay3 = fmaf(wi, hif(v.w), ay3);
        }
        c4 = c4n;
    }
    {
        float yx0 = ax0 + lof(xv.x), yy0 = ay0 + hif(xv.x);
        float yx1 = ax1 + lof(xv.y), yy1 = ay1 + hif(xv.y);
        float yx2 = ax2 + lof(xv.z), yy2 = ay2 + hif(xv.z);
        float yx3 = ax3 + lof(xv.w), yy3 = ay3 + hif(xv.w);
        float ss = yx0 * yx0 + yy0 * yy0 + yx1 * yx1 + yy1 * yy1
                 + yx2 * yx2 + yy2 * yy2 + yx3 * yx3 + yy3 * yy3;
        ss += __shfl_xor(ss, 1); ss += __shfl_xor(ss, 2);
        ss += __shfl_xor(ss, 4); ss += __shfl_xor(ss, 8);
        float inv = 1.0f / fmaxf(sqrtf(ss), 1e-12f);
        uint4 o;
        o.x = pack_bf16x2(yx0 * inv, yy0 * inv);
        o.y = pack_bf16x2(yx1 * inv, yy1 * inv);
        o.z = pack_bf16x2(yx2 * inv, yy2 * inv);
        o.w = pack_bf16x2(yx3 * inv, yy3 * inv);
        if (!LAST && n < NN) *(uint4*)(xb + (size_t)n * 64 + ln15 * 4) = o;
        // LDS A-frag layout (verified): col-pair c2=ln15*4+k of row j; contiguous
        // for k=0..3 -> one ds_write_b128.
        int rt = j >> 4, m = j & 15;
        *(uint4*)&lds_a[(((rt * 4 + (ln15 >> 2)) * 64) + (ln15 & 3) * 16 + m) * 4] = o;
    }
    __syncthreads();

    // ---- phase 2: gemm, wave w = j16 strip w ----
    const short8* A8 = (const short8*)lds_a;
    const short8* B8 = (const short8*)Wp;
    f32x4 acc[2];
    {
        float bv = bias[w * 16 + ln15];
        acc[0] = (f32x4){bv, bv, bv, bv};
        acc[1] = acc[0];
    }
#pragma unroll
    for (int ks = 0; ks < 4; ++ks) {
        short8 b = B8[(ks * 8 + w) * 64 + lane];
#pragma unroll
        for (int rt = 0; rt < 2; ++rt) {
            short8 a = A8[(rt * 4 + ks) * 64 + lane];
            acc[rt] = __builtin_amdgcn_mfma_f32_16x16x32_bf16(a, b, acc[rt], 0, 0, 0);
        }
    }
    if (!LAST) {
        ushort* ob = (ushort*)hb_out;
#pragma unroll
        for (int rt = 0; rt < 2; ++rt) {
#pragma unroll
            for (int reg = 0; reg < 4; ++reg) {
                int nn = n0 + rt * 16 + q * 4 + reg;
                if (nn < NN)
                    ob[(size_t)nn * HID + w * 16 + ln15] = bf16_rne(fmaxf(acc[rt][reg], 0.0f));
            }
        }
    } else {
        // ---- stage h tile into lds_b in A-frag layout (bf16, same rounding as before) ----
        ushort* sb = (ushort*)lds_b;
        int c  = w * 16 + ln15;          // column this thread owns
        int c2 = c >> 1, cb = c2 & 3, cq = (c2 >> 2) & 3, cks = c2 >> 4, lohi = c & 1;
#pragma unroll
        for (int rt = 0; rt < 2; ++rt) {
#pragma unroll
            for (int reg = 0; reg < 4; ++reg) {
                int m = q * 4 + reg;     // row & 15
                int uidx = ((rt * 4 + cks) * 64 + cq * 16 + m) * 4 + cb;
                sb[uidx * 2 + lohi] = bf16_rne(fmaxf(acc[rt][reg], 0.0f));
            }
        }
        __syncthreads();
        // ---- phase 3: lin1 gemm from lds_b ----
        const short8* A8b = (const short8*)lds_b;
        const short8* B8b = (const short8*)Wp2;
        f32x4 acc3[2];
        {
            float bv = bias2[w * 16 + ln15];
            acc3[0] = (f32x4){bv, bv, bv, bv};
            acc3[1] = acc3[0];
        }
#pragma unroll
        for (int ks = 0; ks < 4; ++ks) {
            short8 bb = B8b[(ks * 8 + w) * 64 + lane];
#pragma unroll
            for (int rt = 0; rt < 2; ++rt) {
                short8 a = A8b[(rt * 4 + ks) * 64 + lane];
                acc3[rt] = __builtin_amdgcn_mfma_f32_16x16x32_bf16(a, bb, acc3[rt], 0, 0, 0);
            }
        }
        // ---- projection: s(row) = sum_j relu(h2)_j * wp_j, then graph segment-sum ----
        float wv = wp[w * 16 + ln15];
#pragma unroll
        for (int rt = 0; rt < 2; ++rt) {
#pragma unroll
            for (int reg = 0; reg < 4; ++reg) {
                float p = fmaxf(acc3[rt][reg], 0.0f) * wv;
                p += __shfl_xor(p, 1); p += __shfl_xor(p, 2);
                p += __shfl_xor(p, 4); p += __shfl_xor(p, 8);
                if (ln15 == 0) lds_p[(rt * 16 + q * 4 + reg) * 8 + w] = p;
            }
        }
        __syncthreads();
        if (t < 32) {
            float sm = 0.0f;
#pragma unroll
            for (int k = 0; k < 8; ++k) sm += lds_p[t * 8 + k];
            int nn = n0 + t;
            if (nn < NN) atomicAdd(&grf[batch[nn]], sm);
        }
    }
}

// ---------- out conversion: out[g] = grf[g] + wpb ----------
__global__ void out_k(const float* __restrict__ grf, const float* __restrict__ wpb,
                      void* __restrict__ out, const int* __restrict__ flag) {
    int g = blockIdx.x * 256 + threadIdx.x;
    if (g >= NG) return;
    float r = grf[g] + wpb[0];
    if (*flag) ((float*)out)[g] = r;
    else       ((bf16*)out)[g] = __float2bfloat16(r);
}

extern "C" void kernel_launch(void* const* d_in, const int* in_sizes, int n_in,
                              void* d_out, int out_size, void* d_ws, size_t ws_size,
                              hipStream_t stream) {
    const int*  xo    = (const int*)d_in[0];
    const int*  ei    = (const int*)d_in[1];
    const int*  src   = ei;
    const int*  dst   = ei + NE;
    const void* ea    = d_in[2];
    const int*  batch = (const int*)d_in[3];
    const void* emb   = d_in[4];
    const void* gamw  = d_in[5];
    const void* wAW   = d_in[6];
    const void* wAb   = d_in[7];
    const void* linW  = d_in[8];
    const void* linb  = d_in[9];
    const void* wpW   = d_in[10];
    const void* wpb   = d_in[11];

    uint*  xb     = (uint*)d_ws;                           // NN*64 (12.8 MB)
    uint*  hA     = xb + (size_t)NN * 64;                  // NN*64 (12.8 MB)
    uint*  hB     = hA + (size_t)NN * 64;                  // NN*64 (12.8 MB)
    uint2* rec    = (uint2*)hB;                            // alias: NB*RCAP*8B = 8.0 MB,
                                                           // dead before gg1 writes hB
    uint*  csr    = hB + (size_t)NN * 64;                  // NN*CAP (12.8 MB)
    int*   degarr = (int*)(csr + (size_t)NN * CAP);        // NN
    float* grf    = (float*)(degarr + NN);                 // NG
    float* P      = grf + NG;
    float* f_sgam = P;                 // 300 (+pad)
    float* f_wAb  = f_sgam + 304;      // 384
    float* f_linb = f_wAb + 384;       // 256
    float* f_wp   = f_linb + 256;      // 128
    float* f_wpb  = f_wp + 128;        // 1 (+pad)
    int*   flag   = (int*)(f_wpb + 8);
    ushort* Wp    = (ushort*)(flag + 8);   // 5*16384 bf16
    int*   bcur   = (int*)(Wp + 5 * 16384); // NB bucket cursors (+pad)
    float* gpn    = (float*)(bcur + 128);   // 3*NN per-node sigmoid(gamma)

    hipMemsetAsync(bcur, 0, NB * sizeof(int), stream);

    prep_k<<<PREP_GRID, 256, 0, stream>>>(xo, emb, gamw, wAW, wAb, linW, linb, wpW, wpb,
                                          src, dst, ea,
                                          xb, Wp, f_sgam, f_wAb, f_linb, f_wp, f_wpb,
                                          rec, bcur, gpn, grf, flag);

    // phase-B CSR build (98 bucket blocks) overlapped with gemm layer-1 (xb -> hA)
    work2_k<<<NB + G1_BLKS, 512, 0, stream>>>(xb, Wp, f_wAb, hA, rec, bcur, csr, degarr);

    const int GG_GRID = (NN + 31) / 32;   // 1563
    // gather1(hA) + gemm2 -> hB
    gg_k<0><<<GG_GRID, 512, 0, stream>>>(degarr, csr, gpn,          hA, xb,
                                         Wp + 1 * 16384, f_wAb + 128, hB,
                                         nullptr, nullptr, nullptr, nullptr, nullptr);
    // gather2(hB) + gemm3 -> hA
    gg_k<0><<<GG_GRID, 512, 0, stream>>>(degarr, csr, gpn + NN,     hB, xb,
                                         Wp + 2 * 16384, f_wAb + 256, hA,
                                         nullptr, nullptr, nullptr, nullptr, nullptr);
    // gather3(hA) + gemm4(lin0) + fused gemm5(lin1)+projection -> grf
    gg_k<1><<<GG_GRID, 512, 0, stream>>>(degarr, csr, gpn + 2 * NN, hA, xb,
                                         Wp + 3 * 16384, f_linb,      nullptr,
                                         Wp + 4 * 16384, f_linb + HID, f_wp, batch, grf);

    out_k<<<(NG + 255) / 256, 256, 0, stream>>>(grf, f_wpb, d_out, flag);
}